// Round 16
// baseline (213.197 us; speedup 1.0000x reference)
//
#include <hip/hip_runtime.h>

#define UN      100000
#define IN_     50000
#define DN      64
#define ERATE   1000000
#define ETRUST  500000
#define EPRED   200000
#define LAMDA   0.5f
#define LAMDA_T 0.25f

#define STRIDE_R 48
#define STRIDE_T 32
#define NBUCK    391
#define BCAP_R   3072
#define BCAP_T   1536
#define BCAP_I   6144
#define BCAP_U   1536

// Shared bin-phase offsets
#define OFF_BIN_T_W  (9609216 / 4)
#define OFF_BIN_I_W  (14413824 / 4)
#define OFF_BIN_U_W  (19230720 / 4)
#define OFF_GCURR_W  (21633024 / 4)

// ---- FULL2 layout (ws >= 83,840,016): no overlay for bf16 tables; hb overlays binned ----
#define G_HB_B      0               // 12.8M, overlays dead binned region (post-bin4)
#define G_CSR_R_B   21640000        // u16, 9.6M
#define G_CSR_T_B   31240000        // i32, 12.8M
#define G_DRI_B     44040000
#define G_DTO_B     44240000
#define G_CURR_B    44640000
#define G_CURT_B    45040000
#define G_ACC_B     45440000
#define G_YBI_B     45440016        // 6.4M
#define G_YBU_B     51840016        // 12.8M
#define G_PBU_B     64640016        // 12.8M
#define G_PBI_B     77440016        // 6.4M
#define G_NEED      83840016ULL

// ---- FALLBACK layout (exact R14, proven 199us) ----
#define B_YBI_B     0
#define B_YBU_B     6400000
#define B_HB_B      19200000
#define B_CSR_R_B   32000000
#define B_CSR_T_B   41600000
#define B_DRI_B     54400000
#define B_DTO_B     54600000
#define B_CURR_B    55000000
#define B_CURT_B    55400000
#define B_ACC_B     55800000

#define NB_SCATR 489
#define NB_SCATT 245
#define NB_SCATI 489
#define NB_SCATU 245
#define NB_SCAT_TOT (NB_SCATR + NB_SCATT + NB_SCATI + NB_SCATU)  // 1468
#define NB_BUILD 391
#define NB_CNTI  196
#define NB_CNTU  391
#define NB_CI    3125    // item-table conv blocks
#define NB_CU    6250    // user-table conv blocks
#define NB_CONV_TOT (2 * NB_CI + 2 * NB_CU)                       // 18750
#define NB_LINK  1024
#define NB_GATH  25000
#define NB_SCOR  12500
#define NB_REG   512

__device__ __forceinline__ float degfac_i(int c) {
    return c > 0 ? rsqrtf((float)c) : 0.0f;
}
__device__ __forceinline__ unsigned short f2bf(float x) {
    unsigned u = __float_as_uint(x);
    return (unsigned short)((u + 0x7FFFu + ((u >> 16) & 1u)) >> 16);
}
__device__ __forceinline__ float bf2f(unsigned short b) {
    return __uint_as_float(((unsigned)b) << 16);
}

__global__ void k_zero(int* __restrict__ p, int n) {
    int i = blockIdx.x * blockDim.x + threadIdx.x;
    if (i < n) p[i] = 0;
}

__device__ __forceinline__ void scat_role(const int* __restrict__ key,
                                          const int* __restrict__ val, int n,
                                          int* __restrict__ gcur, int2* __restrict__ binned,
                                          int bcap, int rb) {
    __shared__ int lhist[NBUCK];
    __shared__ int lbase[NBUCK];
    for (int i = threadIdx.x; i < NBUCK; i += 256) lhist[i] = 0;
    __syncthreads();
    int s[8], d[8], rk[8];
    int base_e = rb * 2048;
    #pragma unroll
    for (int k = 0; k < 8; ++k) {
        int i = base_e + k * 256 + threadIdx.x;
        if (i < n) {
            s[k] = key[i];
            d[k] = val[i];
            rk[k] = atomicAdd(&lhist[s[k] >> 8], 1);
        } else s[k] = -1;
    }
    __syncthreads();
    for (int i = threadIdx.x; i < NBUCK; i += 256) {
        int c = lhist[i];
        lbase[i] = c ? atomicAdd(&gcur[i], c) : 0;
    }
    __syncthreads();
    #pragma unroll
    for (int k = 0; k < 8; ++k) {
        if (s[k] >= 0) {
            int b = s[k] >> 8;
            int pos = lbase[b] + rk[k];
            if (pos < bcap) binned[b * bcap + pos] = make_int2(s[k], d[k]);
        }
    }
}

__device__ __forceinline__ void scat_key_role(const int* __restrict__ key, int n,
                                              int* __restrict__ gcur, int* __restrict__ binned,
                                              int bcap, int rb) {
    __shared__ int lhist[NBUCK];
    __shared__ int lbase[NBUCK];
    for (int i = threadIdx.x; i < NBUCK; i += 256) lhist[i] = 0;
    __syncthreads();
    int s[8], rk[8];
    int base_e = rb * 2048;
    #pragma unroll
    for (int k = 0; k < 8; ++k) {
        int i = base_e + k * 256 + threadIdx.x;
        if (i < n) {
            s[k] = key[i];
            rk[k] = atomicAdd(&lhist[s[k] >> 8], 1);
        } else s[k] = -1;
    }
    __syncthreads();
    for (int i = threadIdx.x; i < NBUCK; i += 256) {
        int c = lhist[i];
        lbase[i] = c ? atomicAdd(&gcur[i], c) : 0;
    }
    __syncthreads();
    #pragma unroll
    for (int k = 0; k < 8; ++k) {
        if (s[k] >= 0) {
            int b = s[k] >> 8;
            int pos = lbase[b] + rk[k];
            if (pos < bcap) binned[b * bcap + pos] = s[k];
        }
    }
}

__device__ __forceinline__ void conv_role(const float4* __restrict__ src,
                                          ushort4* __restrict__ dst, int n4, int rb) {
    int i = rb * 256 + threadIdx.x;
    if (i < n4) {
        float4 v = src[i];
        dst[i] = make_ushort4(f2bf(v.x), f2bf(v.y), f2bf(v.z), f2bf(v.w));
    }
}

// bin3: scatR | scatT | scatI | scatU | [fused conv of 4 tables -> fresh space]
__global__ __launch_bounds__(256) void k_bin3(
        const int* __restrict__ rate_src, const int* __restrict__ rate_dst,
        const int* __restrict__ trust_src, const int* __restrict__ trust_dst,
        int* __restrict__ gcur_r, int2* __restrict__ binned_r,
        int* __restrict__ gcur_t, int2* __restrict__ binned_t,
        int* __restrict__ gcur_i, int* __restrict__ binned_i,
        int* __restrict__ gcur_u, int* __restrict__ binned_u,
        const float4* __restrict__ yw_item, const float4* __restrict__ yw_user,
        const float4* __restrict__ pq_user, const float4* __restrict__ pq_item,
        ushort4* __restrict__ yb_item, ushort4* __restrict__ yb_user,
        ushort4* __restrict__ pb_user, ushort4* __restrict__ pb_item) {
    int b = blockIdx.x;
    if (b < NB_SCATR) {
        scat_role(rate_src, rate_dst, ERATE, gcur_r, binned_r, BCAP_R, b);
    } else if (b < NB_SCATR + NB_SCATT) {
        scat_role(trust_dst, trust_src, ETRUST, gcur_t, binned_t, BCAP_T, b - NB_SCATR);
    } else if (b < NB_SCATR + NB_SCATT + NB_SCATI) {
        scat_key_role(rate_dst, ERATE, gcur_i, binned_i, BCAP_I, b - NB_SCATR - NB_SCATT);
    } else if (b < NB_SCAT_TOT) {
        scat_key_role(trust_src, ETRUST, gcur_u, binned_u, BCAP_U,
                      b - NB_SCATR - NB_SCATT - NB_SCATI);
    } else {
        int b2 = b - NB_SCAT_TOT;   // only present in FULL2 grid
        if (b2 < NB_CI)                  conv_role(yw_item, yb_item, IN_ * DN / 4, b2);
        else if (b2 < NB_CI + NB_CU)     conv_role(yw_user, yb_user, UN * DN / 4, b2 - NB_CI);
        else if (b2 < NB_CI + 2 * NB_CU) conv_role(pq_user, pb_user, UN * DN / 4, b2 - NB_CI - NB_CU);
        else                             conv_role(pq_item, pb_item, IN_ * DN / 4, b2 - NB_CI - 2 * NB_CU);
    }
}

__device__ __forceinline__ void build_role_u16(const int2* __restrict__ binned, int bcap,
                                               const int* __restrict__ gcur,
                                               unsigned short* __restrict__ csr, int stride_c,
                                               int* __restrict__ cur_out, int b) {
    __shared__ int lcur[256];
    lcur[threadIdx.x] = 0;
    __syncthreads();
    int cnt = gcur[b]; if (cnt > bcap) cnt = bcap;
    for (int i = threadIdx.x; i < cnt; i += 256) {
        int2 e = binned[b * bcap + i];
        int u = e.x & 255;
        int p = atomicAdd(&lcur[u], 1);
        if (p < stride_c) csr[e.x * stride_c + p] = (unsigned short)e.y;
    }
    __syncthreads();
    int u = (b << 8) + threadIdx.x;
    if (u < UN) cur_out[u] = lcur[threadIdx.x];
}

__device__ __forceinline__ void build_role_i32(const int2* __restrict__ binned, int bcap,
                                               const int* __restrict__ gcur,
                                               int* __restrict__ csr, int stride_c,
                                               int* __restrict__ cur_out, int b) {
    __shared__ int lcur[256];
    lcur[threadIdx.x] = 0;
    __syncthreads();
    int cnt = gcur[b]; if (cnt > bcap) cnt = bcap;
    for (int i = threadIdx.x; i < cnt; i += 256) {
        int2 e = binned[b * bcap + i];
        int u = e.x & 255;
        int p = atomicAdd(&lcur[u], 1);
        if (p < stride_c) csr[e.x * stride_c + p] = e.y;
    }
    __syncthreads();
    int u = (b << 8) + threadIdx.x;
    if (u < UN) cur_out[u] = lcur[threadIdx.x];
}

__device__ __forceinline__ void count_role(const int* __restrict__ binned, int bcap,
                                           const int* __restrict__ gcur,
                                           int* __restrict__ deg_out, int limit, int b) {
    __shared__ int lcnt[256];
    lcnt[threadIdx.x] = 0;
    __syncthreads();
    int cnt = gcur[b]; if (cnt > bcap) cnt = bcap;
    for (int i = threadIdx.x; i < cnt; i += 256)
        atomicAdd(&lcnt[binned[b * bcap + i] & 255], 1);
    __syncthreads();
    int u = (b << 8) + threadIdx.x;
    if (u < limit) deg_out[u] = lcnt[threadIdx.x];
}

__global__ __launch_bounds__(256) void k_bin4(
        const int2* __restrict__ binned_r, const int* __restrict__ gcur_r,
        const int2* __restrict__ binned_t, const int* __restrict__ gcur_t,
        const int* __restrict__ binned_i, const int* __restrict__ gcur_i,
        const int* __restrict__ binned_u, const int* __restrict__ gcur_u,
        unsigned short* __restrict__ csr_r, int* __restrict__ cur_r,
        int* __restrict__ csr_t, int* __restrict__ cur_t,
        int* __restrict__ dri, int* __restrict__ dto) {
    int b = blockIdx.x;
    if (b < NB_BUILD) {
        build_role_u16(binned_r, BCAP_R, gcur_r, csr_r, STRIDE_R, cur_r, b);
    } else if (b < 2 * NB_BUILD) {
        build_role_i32(binned_t, BCAP_T, gcur_t, csr_t, STRIDE_T, cur_t, b - NB_BUILD);
    } else if (b < 2 * NB_BUILD + NB_CNTI) {
        count_role(binned_i, BCAP_I, gcur_i, dri, IN_, b - 2 * NB_BUILD);
    } else {
        count_role(binned_u, BCAP_U, gcur_u, dto, UN, b - 2 * NB_BUILD - NB_CNTI);
    }
}

// FALLBACK conv: 2 tables (R14)
__global__ __launch_bounds__(256) void k_conv2(
        const float4* __restrict__ yw_item, const float4* __restrict__ yw_user,
        ushort4* __restrict__ yb_item, ushort4* __restrict__ yb_user) {
    int b = blockIdx.x;
    if (b < NB_CI) conv_role(yw_item, yb_item, IN_ * DN / 4, b);
    else           conv_role(yw_user, yb_user, UN * DN / 4, b - NB_CI);
}

// FULL gathB: all-bf16
__global__ __launch_bounds__(256) void k_gathB_full(
        const unsigned short* __restrict__ pb_user, const unsigned short* __restrict__ yb_item,
        const unsigned short* __restrict__ yb_user,
        const int* __restrict__ cur_r, const unsigned short* __restrict__ csr_r,
        const int* __restrict__ cur_t, const int* __restrict__ csr_t,
        const int* __restrict__ trust_src, const int* __restrict__ trust_dst,
        double* __restrict__ acc,
        unsigned short* __restrict__ hb) {
    int b = blockIdx.x;
    if (b < NB_LINK) {
        int stride = NB_LINK * 256;
        float local = 0.0f;
        const int TOT = ETRUST * 16;
        for (int tid = b * 256 + threadIdx.x; tid < TOT; tid += stride) {
            int e = tid >> 4;
            int c = (tid & 15) << 2;
            int s = trust_src[e], d = trust_dst[e];
            ushort4 a = *reinterpret_cast<const ushort4*>(yb_user + ((long)s << 6) + c);
            ushort4 bb = *reinterpret_cast<const ushort4*>(pb_user + ((long)d << 6) + c);
            float dot = bf2f(a.x) * bf2f(bb.x) + bf2f(a.y) * bf2f(bb.y)
                      + bf2f(a.z) * bf2f(bb.z) + bf2f(a.w) * bf2f(bb.w);
            #pragma unroll
            for (int off = 1; off < 16; off <<= 1) dot += __shfl_xor(dot, off);
            if ((tid & 15) == 0) { float dm = dot - 1.0f; local += dm * dm; }
        }
        #pragma unroll
        for (int off = 32; off > 0; off >>= 1) local += __shfl_xor(local, off);
        __shared__ float red[4];
        if ((threadIdx.x & 63) == 0) red[threadIdx.x >> 6] = local;
        __syncthreads();
        if (threadIdx.x == 0) unsafeAtomicAdd(acc, (double)(red[0] + red[1] + red[2] + red[3]));
        return;
    }
    int w = ((b - NB_LINK) << 2) + (threadIdx.x >> 6);
    if (w >= UN) return;
    int lane = threadIdx.x & 63;
    int grp = lane >> 4;
    int c4 = (lane & 15) << 2;

    float ax = 0.f, ay = 0.f, az = 0.f, aw = 0.f;
    float bx = 0.f, by = 0.f, bz = 0.f, bw = 0.f;
    float tx = 0.f, ty = 0.f, tz = 0.f, tw = 0.f;
    float ux = 0.f, uy = 0.f, uz = 0.f, uw = 0.f;
    int cr = cur_r[w]; if (cr > STRIDE_R) cr = STRIDE_R;
    int ct = cur_t[w]; if (ct > STRIDE_T) ct = STRIDE_T;

    {
        int my = (lane < cr) ? (int)csr_r[w * STRIDE_R + lane] : 0;
        for (int j = 0; j < cr; j += 8) {
            int e0 = j + grp;
            int e1 = j + 4 + grp;
            int r0 = __shfl(my, e0);       // full-wave shfl, sources defined
            int r1 = __shfl(my, e1);
            if (e0 < cr) {
                ushort4 v = *reinterpret_cast<const ushort4*>(yb_item + ((long)r0 << 6) + c4);
                ax += bf2f(v.x); ay += bf2f(v.y); az += bf2f(v.z); aw += bf2f(v.w);
            }
            if (e1 < cr) {
                ushort4 v = *reinterpret_cast<const ushort4*>(yb_item + ((long)r1 << 6) + c4);
                bx += bf2f(v.x); by += bf2f(v.y); bz += bf2f(v.z); bw += bf2f(v.w);
            }
        }
    }
    {
        int my = (lane < ct) ? csr_t[w * STRIDE_T + lane] : 0;
        for (int j = 0; j < ct; j += 8) {
            int e0 = j + grp;
            int e1 = j + 4 + grp;
            int r0 = __shfl(my, e0);
            int r1 = __shfl(my, e1);
            if (e0 < ct) {
                ushort4 v = *reinterpret_cast<const ushort4*>(yb_user + ((long)r0 << 6) + c4);
                tx += bf2f(v.x); ty += bf2f(v.y); tz += bf2f(v.z); tw += bf2f(v.w);
            }
            if (e1 < ct) {
                ushort4 v = *reinterpret_cast<const ushort4*>(yb_user + ((long)r1 << 6) + c4);
                ux += bf2f(v.x); uy += bf2f(v.y); uz += bf2f(v.z); uw += bf2f(v.w);
            }
        }
    }
    float fr = degfac_i(cr), ft = degfac_i(ct);
    float rx = fr * (ax + bx) + ft * (tx + ux);
    float ry = fr * (ay + by) + ft * (ty + uy);
    float rz = fr * (az + bz) + ft * (tz + uz);
    float rw = fr * (aw + bw) + ft * (tw + uw);
    rx += __shfl_xor(rx, 16); rx += __shfl_xor(rx, 32);
    ry += __shfl_xor(ry, 16); ry += __shfl_xor(ry, 32);
    rz += __shfl_xor(rz, 16); rz += __shfl_xor(rz, 32);
    rw += __shfl_xor(rw, 16); rw += __shfl_xor(rw, 32);
    if (grp == 0) {
        ushort4 p = *reinterpret_cast<const ushort4*>(pb_user + ((long)w << 6) + c4);
        ushort4 o4 = make_ushort4(f2bf(bf2f(p.x) + rx), f2bf(bf2f(p.y) + ry),
                                  f2bf(bf2f(p.z) + rz), f2bf(bf2f(p.w) + rw));
        *reinterpret_cast<ushort4*>(hb + ((long)w << 6) + c4) = o4;
    }
}

// FALLBACK gathB: exact R14 (f32 pq_user)
__global__ __launch_bounds__(256) void k_gathB_fb(
        const float* __restrict__ pq_user, const unsigned short* __restrict__ yb_item,
        const unsigned short* __restrict__ yb_user,
        const int* __restrict__ cur_r, const unsigned short* __restrict__ csr_r,
        const int* __restrict__ cur_t, const int* __restrict__ csr_t,
        const int* __restrict__ trust_src, const int* __restrict__ trust_dst,
        double* __restrict__ acc,
        unsigned short* __restrict__ hb) {
    int b = blockIdx.x;
    if (b < NB_LINK) {
        int stride = NB_LINK * 256;
        float local = 0.0f;
        const int TOT = ETRUST * 16;
        for (int tid = b * 256 + threadIdx.x; tid < TOT; tid += stride) {
            int e = tid >> 4;
            int c = (tid & 15) << 2;
            int s = trust_src[e], d = trust_dst[e];
            ushort4 a = *reinterpret_cast<const ushort4*>(yb_user + ((long)s << 6) + c);
            float4 bb = *reinterpret_cast<const float4*>(pq_user + ((long)d << 6) + c);
            float dot = bf2f(a.x) * bb.x + bf2f(a.y) * bb.y
                      + bf2f(a.z) * bb.z + bf2f(a.w) * bb.w;
            #pragma unroll
            for (int off = 1; off < 16; off <<= 1) dot += __shfl_xor(dot, off);
            if ((tid & 15) == 0) { float dm = dot - 1.0f; local += dm * dm; }
        }
        #pragma unroll
        for (int off = 32; off > 0; off >>= 1) local += __shfl_xor(local, off);
        __shared__ float red[4];
        if ((threadIdx.x & 63) == 0) red[threadIdx.x >> 6] = local;
        __syncthreads();
        if (threadIdx.x == 0) unsafeAtomicAdd(acc, (double)(red[0] + red[1] + red[2] + red[3]));
        return;
    }
    int w = ((b - NB_LINK) << 2) + (threadIdx.x >> 6);
    if (w >= UN) return;
    int lane = threadIdx.x & 63;
    int grp = lane >> 4;
    int c4 = (lane & 15) << 2;

    float ax = 0.f, ay = 0.f, az = 0.f, aw = 0.f;
    float bx = 0.f, by = 0.f, bz = 0.f, bw = 0.f;
    float tx = 0.f, ty = 0.f, tz = 0.f, tw = 0.f;
    float ux = 0.f, uy = 0.f, uz = 0.f, uw = 0.f;
    int cr = cur_r[w]; if (cr > STRIDE_R) cr = STRIDE_R;
    int ct = cur_t[w]; if (ct > STRIDE_T) ct = STRIDE_T;

    {
        int my = (lane < cr) ? (int)csr_r[w * STRIDE_R + lane] : 0;
        for (int j = 0; j < cr; j += 8) {
            int e0 = j + grp;
            int e1 = j + 4 + grp;
            int r0 = __shfl(my, e0);
            int r1 = __shfl(my, e1);
            if (e0 < cr) {
                ushort4 v = *reinterpret_cast<const ushort4*>(yb_item + ((long)r0 << 6) + c4);
                ax += bf2f(v.x); ay += bf2f(v.y); az += bf2f(v.z); aw += bf2f(v.w);
            }
            if (e1 < cr) {
                ushort4 v = *reinterpret_cast<const ushort4*>(yb_item + ((long)r1 << 6) + c4);
                bx += bf2f(v.x); by += bf2f(v.y); bz += bf2f(v.z); bw += bf2f(v.w);
            }
        }
    }
    {
        int my = (lane < ct) ? csr_t[w * STRIDE_T + lane] : 0;
        for (int j = 0; j < ct; j += 8) {
            int e0 = j + grp;
            int e1 = j + 4 + grp;
            int r0 = __shfl(my, e0);
            int r1 = __shfl(my, e1);
            if (e0 < ct) {
                ushort4 v = *reinterpret_cast<const ushort4*>(yb_user + ((long)r0 << 6) + c4);
                tx += bf2f(v.x); ty += bf2f(v.y); tz += bf2f(v.z); tw += bf2f(v.w);
            }
            if (e1 < ct) {
                ushort4 v = *reinterpret_cast<const ushort4*>(yb_user + ((long)r1 << 6) + c4);
                ux += bf2f(v.x); uy += bf2f(v.y); uz += bf2f(v.z); uw += bf2f(v.w);
            }
        }
    }
    float fr = degfac_i(cr), ft = degfac_i(ct);
    float rx = fr * (ax + bx) + ft * (tx + ux);
    float ry = fr * (ay + by) + ft * (ty + uy);
    float rz = fr * (az + bz) + ft * (tz + uz);
    float rw = fr * (aw + bw) + ft * (tw + uw);
    rx += __shfl_xor(rx, 16); rx += __shfl_xor(rx, 32);
    ry += __shfl_xor(ry, 16); ry += __shfl_xor(ry, 32);
    rz += __shfl_xor(rz, 16); rz += __shfl_xor(rz, 32);
    rw += __shfl_xor(rw, 16); rw += __shfl_xor(rw, 32);
    if (grp == 0) {
        const float4 p = *reinterpret_cast<const float4*>(pq_user + ((long)w << 6) + c4);
        ushort4 o4 = make_ushort4(f2bf(p.x + rx), f2bf(p.y + ry),
                                  f2bf(p.z + rz), f2bf(p.w + rw));
        *reinterpret_cast<ushort4*>(hb + ((long)w << 6) + c4) = o4;
    }
}

// C: scores (bf16 h x [pb_item bf16 | pq_item f32]) | reg-loss (f32)
__global__ __launch_bounds__(256) void k_scorC(
        const unsigned short* __restrict__ hb, const unsigned short* __restrict__ pb_item,
        int use_pb,
        const float* __restrict__ pq_user, const float* __restrict__ yw_user,
        const float* __restrict__ pq_item, const float* __restrict__ yw_item,
        const float* __restrict__ b_user, const float* __restrict__ b_item,
        const float* __restrict__ gb,
        const int* __restrict__ ps, const int* __restrict__ pd,
        const int* __restrict__ ns, const int* __restrict__ nd,
        const int* __restrict__ cur_r, const int* __restrict__ cur_t,
        const int* __restrict__ dto, const int* __restrict__ dri,
        double* __restrict__ acc, float* __restrict__ out) {
    int b = blockIdx.x;
    if (b < NB_SCOR) {
        int g = (b * 256 + threadIdx.x) >> 4;
        int c = (threadIdx.x & 15) << 2;
        int e0 = g * 2, e1 = g * 2 + 1;
        bool p0 = e0 < EPRED, p1 = e1 < EPRED;
        int i0 = p0 ? e0 : e0 - EPRED;
        int i1 = p1 ? e1 : e1 - EPRED;
        int s0 = (p0 ? ps : ns)[i0];
        int d0 = (p0 ? pd : nd)[i0];
        int s1 = (p1 ? ps : ns)[i1];
        int d1 = (p1 ? pd : nd)[i1];
        ushort4 ha = *reinterpret_cast<const ushort4*>(hb + ((long)s0 << 6) + c);
        ushort4 hc = *reinterpret_cast<const ushort4*>(hb + ((long)s1 << 6) + c);
        float iax, iay, iaz, iaw, ibx, iby, ibz, ibw;
        if (use_pb) {
            ushort4 ia = *reinterpret_cast<const ushort4*>(pb_item + ((long)d0 << 6) + c);
            ushort4 ib = *reinterpret_cast<const ushort4*>(pb_item + ((long)d1 << 6) + c);
            iax = bf2f(ia.x); iay = bf2f(ia.y); iaz = bf2f(ia.z); iaw = bf2f(ia.w);
            ibx = bf2f(ib.x); iby = bf2f(ib.y); ibz = bf2f(ib.z); ibw = bf2f(ib.w);
        } else {
            float4 ia = *reinterpret_cast<const float4*>(pq_item + ((long)d0 << 6) + c);
            float4 ib = *reinterpret_cast<const float4*>(pq_item + ((long)d1 << 6) + c);
            iax = ia.x; iay = ia.y; iaz = ia.z; iaw = ia.w;
            ibx = ib.x; iby = ib.y; ibz = ib.z; ibw = ib.w;
        }
        float dot0 = bf2f(ha.x) * iax + bf2f(ha.y) * iay
                   + bf2f(ha.z) * iaz + bf2f(ha.w) * iaw;
        float dot1 = bf2f(hc.x) * ibx + bf2f(hc.y) * iby
                   + bf2f(hc.z) * ibz + bf2f(hc.w) * ibw;
        #pragma unroll
        for (int off = 1; off < 16; off <<= 1) {
            dot0 += __shfl_xor(dot0, off);
            dot1 += __shfl_xor(dot1, off);
        }
        if ((threadIdx.x & 15) == 0) {
            float g0 = gb[0];
            float2 o2 = make_float2(dot0 + b_user[s0] + b_item[d0] + g0,
                                    dot1 + b_user[s1] + b_item[d1] + g0);
            *reinterpret_cast<float2*>(out + e0) = o2;
        }
    } else {
        int rb = b - NB_SCOR;
        int stride = NB_REG * 256;
        float local = 0.0f;
        const int TOT = (UN + IN_) * 16;
        for (int tid = rb * 256 + threadIdx.x; tid < TOT; tid += stride) {
            int r = tid >> 4;
            int c = (tid & 15) << 2;
            if (r < UN) {
                float4 p = *reinterpret_cast<const float4*>(pq_user + ((long)r << 6) + c);
                float4 y = *reinterpret_cast<const float4*>(yw_user + ((long)r << 6) + c);
                float sp = p.x * p.x + p.y * p.y + p.z * p.z + p.w * p.w;
                float sy = y.x * y.x + y.y * y.y + y.z * y.z + y.w * y.w;
                #pragma unroll
                for (int off = 1; off < 16; off <<= 1) {
                    sp += __shfl_xor(sp, off);
                    sy += __shfl_xor(sy, off);
                }
                if ((tid & 15) == 0) {
                    float Iu  = degfac_i(cur_r[r]);
                    float Tu  = degfac_i(cur_t[r]);
                    float Tvp = degfac_i(dto[r]);
                    float bb  = b_user[r];
                    local += ((LAMDA * Iu) * (bb * bb)
                            + (LAMDA * Iu + LAMDA_T * Tu) * sp
                            + (LAMDA_T * Tvp) * sy) * (1.0f / UN);
                }
            } else {
                int it = r - UN;
                float4 p = *reinterpret_cast<const float4*>(pq_item + ((long)it << 6) + c);
                float4 y = *reinterpret_cast<const float4*>(yw_item + ((long)it << 6) + c);
                float sp = p.x * p.x + p.y * p.y + p.z * p.z + p.w * p.w;
                float sy = y.x * y.x + y.y * y.y + y.z * y.z + y.w * y.w;
                #pragma unroll
                for (int off = 1; off < 16; off <<= 1) {
                    sp += __shfl_xor(sp, off);
                    sy += __shfl_xor(sy, off);
                }
                if ((tid & 15) == 0) {
                    float Uj = degfac_i(dri[it]);
                    float bb = b_item[it];
                    local += (LAMDA * Uj) * (bb * bb + sp + sy) * (1.0f / IN_);
                }
            }
        }
        #pragma unroll
        for (int off = 32; off > 0; off >>= 1) local += __shfl_xor(local, off);
        __shared__ float red[4];
        if ((threadIdx.x & 63) == 0) red[threadIdx.x >> 6] = local;
        __syncthreads();
        if (threadIdx.x == 0) unsafeAtomicAdd(acc + 1, (double)(red[0] + red[1] + red[2] + red[3]));
    }
}

__global__ void k_final(const double* __restrict__ acc, float* __restrict__ out) {
    if (threadIdx.x == 0 && blockIdx.x == 0) {
        out[2 * EPRED]     = (float)acc[1];
        out[2 * EPRED + 1] = (float)(LAMDA_T * acc[0] / (double)ETRUST);
    }
}

extern "C" void kernel_launch(void* const* d_in, const int* in_sizes, int n_in,
                              void* d_out, int out_size, void* d_ws, size_t ws_size,
                              hipStream_t stream) {
    const float* pq_user = (const float*)d_in[0];
    const float* pq_item = (const float*)d_in[1];
    const float* yw_user = (const float*)d_in[2];
    const float* yw_item = (const float*)d_in[3];
    const float* b_user  = (const float*)d_in[4];
    const float* b_item  = (const float*)d_in[5];
    const float* gb      = (const float*)d_in[6];
    const int* rate_src  = (const int*)d_in[7];
    const int* rate_dst  = (const int*)d_in[8];
    const int* trust_src = (const int*)d_in[9];
    const int* trust_dst = (const int*)d_in[10];
    const int* pos_src   = (const int*)d_in[11];
    const int* pos_dst   = (const int*)d_in[12];
    const int* neg_src   = (const int*)d_in[13];
    const int* neg_dst   = (const int*)d_in[14];

    char*  wsb = (char*)d_ws;
    int*   wsi = (int*)d_ws;
    int2*  binned_r = (int2*)wsi;
    int2*  binned_t = (int2*)(wsi + OFF_BIN_T_W);
    int*   binned_i = wsi + OFF_BIN_I_W;
    int*   binned_u = wsi + OFF_BIN_U_W;
    int*   gcur_r = wsi + OFF_GCURR_W;
    int*   gcur_t = gcur_r + 400;
    int*   gcur_i = gcur_t + 400;
    int*   gcur_u = gcur_i + 200;
    float* out = (float*)d_out;

    bool full = (ws_size >= G_NEED);

    if (full) {
        unsigned short* csr_r  = (unsigned short*)(wsb + G_CSR_R_B);
        int*   csr_t  = (int*)(wsb + G_CSR_T_B);
        int*   dri    = (int*)(wsb + G_DRI_B);
        int*   dto    = (int*)(wsb + G_DTO_B);
        int*   cur_r  = (int*)(wsb + G_CURR_B);
        int*   cur_t  = (int*)(wsb + G_CURT_B);
        double* acc   = (double*)(wsb + G_ACC_B);
        unsigned short* yb_item = (unsigned short*)(wsb + G_YBI_B);
        unsigned short* yb_user = (unsigned short*)(wsb + G_YBU_B);
        unsigned short* pb_user = (unsigned short*)(wsb + G_PBU_B);
        unsigned short* pb_item = (unsigned short*)(wsb + G_PBI_B);
        unsigned short* hb      = (unsigned short*)(wsb + G_HB_B);

        k_zero<<<6, 256, 0, stream>>>(gcur_r, 1400);
        k_zero<<<1, 64, 0, stream>>>((int*)acc, 4);
        // bin3 with fused 4-table bf16 conversion (conv roles write fresh space only)
        k_bin3<<<NB_SCAT_TOT + NB_CONV_TOT, 256, 0, stream>>>(
            rate_src, rate_dst, trust_src, trust_dst,
            gcur_r, binned_r, gcur_t, binned_t,
            gcur_i, binned_i, gcur_u, binned_u,
            (const float4*)yw_item, (const float4*)yw_user,
            (const float4*)pq_user, (const float4*)pq_item,
            (ushort4*)yb_item, (ushort4*)yb_user,
            (ushort4*)pb_user, (ushort4*)pb_item);
        k_bin4<<<2 * NB_BUILD + NB_CNTI + NB_CNTU, 256, 0, stream>>>(
            binned_r, gcur_r, binned_t, gcur_t, binned_i, gcur_i, binned_u, gcur_u,
            csr_r, cur_r, csr_t, cur_t, dri, dto);
        k_gathB_full<<<NB_LINK + NB_GATH, 256, 0, stream>>>(
            pb_user, yb_item, yb_user, cur_r, csr_r, cur_t, csr_t,
            trust_src, trust_dst, acc, hb);
        k_scorC<<<NB_SCOR + NB_REG, 256, 0, stream>>>(
            hb, pb_item, 1, pq_user, yw_user, pq_item, yw_item, b_user, b_item, gb,
            pos_src, pos_dst, neg_src, neg_dst,
            cur_r, cur_t, dto, dri, acc, out);
        k_final<<<1, 64, 0, stream>>>(acc, out);
    } else {
        unsigned short* csr_r  = (unsigned short*)(wsb + B_CSR_R_B);
        int*   csr_t  = (int*)(wsb + B_CSR_T_B);
        int*   dri    = (int*)(wsb + B_DRI_B);
        int*   dto    = (int*)(wsb + B_DTO_B);
        int*   cur_r  = (int*)(wsb + B_CURR_B);
        int*   cur_t  = (int*)(wsb + B_CURT_B);
        double* acc   = (double*)(wsb + B_ACC_B);
        unsigned short* yb_item = (unsigned short*)(wsb + B_YBI_B);
        unsigned short* yb_user = (unsigned short*)(wsb + B_YBU_B);
        unsigned short* hb      = (unsigned short*)(wsb + B_HB_B);

        k_zero<<<6, 256, 0, stream>>>(gcur_r, 1400);
        k_zero<<<1, 64, 0, stream>>>((int*)acc, 4);
        k_bin3<<<NB_SCAT_TOT, 256, 0, stream>>>(
            rate_src, rate_dst, trust_src, trust_dst,
            gcur_r, binned_r, gcur_t, binned_t,
            gcur_i, binned_i, gcur_u, binned_u,
            nullptr, nullptr, nullptr, nullptr,
            nullptr, nullptr, nullptr, nullptr);
        k_bin4<<<2 * NB_BUILD + NB_CNTI + NB_CNTU, 256, 0, stream>>>(
            binned_r, gcur_r, binned_t, gcur_t, binned_i, gcur_i, binned_u, gcur_u,
            csr_r, cur_r, csr_t, cur_t, dri, dto);
        k_conv2<<<NB_CI + NB_CU, 256, 0, stream>>>(
            (const float4*)yw_item, (const float4*)yw_user,
            (ushort4*)yb_item, (ushort4*)yb_user);
        k_gathB_fb<<<NB_LINK + NB_GATH, 256, 0, stream>>>(
            pq_user, yb_item, yb_user, cur_r, csr_r, cur_t, csr_t,
            trust_src, trust_dst, acc, hb);
        k_scorC<<<NB_SCOR + NB_REG, 256, 0, stream>>>(
            hb, (const unsigned short*)hb, 0, pq_user, yw_user, pq_item, yw_item,
            b_user, b_item, gb, pos_src, pos_dst, neg_src, neg_dst,
            cur_r, cur_t, dto, dri, acc, out);
        k_final<<<1, 64, 0, stream>>>(acc, out);
    }
}

// Round 17
// 198.958 us; speedup vs baseline: 1.0716x; 1.0716x over previous
//
#include <hip/hip_runtime.h>

#define UN      100000
#define IN_     50000
#define DN      64
#define ERATE   1000000
#define ETRUST  500000
#define EPRED   200000
#define LAMDA   0.5f
#define LAMDA_T 0.25f

#define STRIDE_R 48
#define STRIDE_T 32
#define NBUCK    391
#define BCAP_R   3072
#define BCAP_T   1536
#define BCAP_I   6144
#define BCAP_U   1536

// d_ws layout (byte offsets):
//   bin3/bin4 phase (region 0..21,638,624, dead afterwards):
//     0           binned_r [391*3072] int2   9,609,216
//     9,609,216   binned_t [391*1536] int2   4,804,608
//     14,413,824  binned_i [196*6144] i32    4,816,896
//     19,230,720  binned_u [391*1536] i32    2,402,304
//     21,633,024  gcur_r/t/i/u               5,600 (1400 words, zeroed)
//   post-bin4 (conv/gathB/scorC) reuse of 0..32,000,000:
//     0           yb_item [IN_*64] bf16      6,400,000
//     6,400,000   yb_user [UN*64]  bf16     12,800,000
//     19,200,000  hb      [UN*64]  bf16     12,800,000
//   32,000,000  csr_r [UN*48] u16    9,600,000
//   41,600,000  csr_t [UN*32] i32   12,800,000
//   54,400,000  dri [IN_] i32 ; 54,600,000 dto [UN] i32
//   55,000,000  cur_r [UN] i32 ; 55,400,000 cur_t [UN] i32
//   55,800,000  acc [2] f64
#define OFF_BIN_T_W  (9609216 / 4)
#define OFF_BIN_I_W  (14413824 / 4)
#define OFF_BIN_U_W  (19230720 / 4)
#define OFF_GCURR_W  (21633024 / 4)
#define OFF_GCURT_W  (21634624 / 4)
#define OFF_GCURI_W  (21636224 / 4)
#define OFF_GCURU_W  (21637024 / 4)
#define OFF_YBU_B    6400000
#define OFF_HB_B     19200000
#define OFF_CSR_R_B  32000000
#define OFF_CSR_T    (41600000 / 4)
#define OFF_DRI      (54400000 / 4)
#define OFF_DTO      (54600000 / 4)
#define OFF_CURR     (55000000 / 4)
#define OFF_CURT     (55400000 / 4)
#define OFF_ACC_B    55800000

#define NB_SCATR 489
#define NB_SCATT 245
#define NB_SCATI 489
#define NB_SCATU 245
#define NB_BUILD 391
#define NB_CNTI  196
#define NB_CNTU  391
#define NB_CONVI 3125    // IN_*64/4/256
#define NB_CONVU 6250    // UN*64/4/256
#define NB_LINK  1024
#define NB_GATH  25000
#define NB_SCOR  12500
#define NB_REG   512

__device__ __forceinline__ float degfac_i(int c) {
    return c > 0 ? rsqrtf((float)c) : 0.0f;
}
__device__ __forceinline__ unsigned short f2bf(float x) {
    unsigned u = __float_as_uint(x);
    return (unsigned short)((u + 0x7FFFu + ((u >> 16) & 1u)) >> 16);
}
__device__ __forceinline__ float bf2f(unsigned short b) {
    return __uint_as_float(((unsigned)b) << 16);
}

__global__ void k_zero(int* __restrict__ p, int n) {
    int i = blockIdx.x * blockDim.x + threadIdx.x;
    if (i < n) p[i] = 0;
}

__device__ __forceinline__ void scat_role(const int* __restrict__ key,
                                          const int* __restrict__ val, int n,
                                          int* __restrict__ gcur, int2* __restrict__ binned,
                                          int bcap, int rb) {
    __shared__ int lhist[NBUCK];
    __shared__ int lbase[NBUCK];
    for (int i = threadIdx.x; i < NBUCK; i += 256) lhist[i] = 0;
    __syncthreads();
    int s[8], d[8], rk[8];
    int base_e = rb * 2048;
    #pragma unroll
    for (int k = 0; k < 8; ++k) {
        int i = base_e + k * 256 + threadIdx.x;
        if (i < n) {
            s[k] = key[i];
            d[k] = val[i];
            rk[k] = atomicAdd(&lhist[s[k] >> 8], 1);
        } else s[k] = -1;
    }
    __syncthreads();
    for (int i = threadIdx.x; i < NBUCK; i += 256) {
        int c = lhist[i];
        lbase[i] = c ? atomicAdd(&gcur[i], c) : 0;
    }
    __syncthreads();
    #pragma unroll
    for (int k = 0; k < 8; ++k) {
        if (s[k] >= 0) {
            int b = s[k] >> 8;
            int pos = lbase[b] + rk[k];
            if (pos < bcap) binned[b * bcap + pos] = make_int2(s[k], d[k]);
        }
    }
}

__device__ __forceinline__ void scat_key_role(const int* __restrict__ key, int n,
                                              int* __restrict__ gcur, int* __restrict__ binned,
                                              int bcap, int rb) {
    __shared__ int lhist[NBUCK];
    __shared__ int lbase[NBUCK];
    for (int i = threadIdx.x; i < NBUCK; i += 256) lhist[i] = 0;
    __syncthreads();
    int s[8], rk[8];
    int base_e = rb * 2048;
    #pragma unroll
    for (int k = 0; k < 8; ++k) {
        int i = base_e + k * 256 + threadIdx.x;
        if (i < n) {
            s[k] = key[i];
            rk[k] = atomicAdd(&lhist[s[k] >> 8], 1);
        } else s[k] = -1;
    }
    __syncthreads();
    for (int i = threadIdx.x; i < NBUCK; i += 256) {
        int c = lhist[i];
        lbase[i] = c ? atomicAdd(&gcur[i], c) : 0;
    }
    __syncthreads();
    #pragma unroll
    for (int k = 0; k < 8; ++k) {
        if (s[k] >= 0) {
            int b = s[k] >> 8;
            int pos = lbase[b] + rk[k];
            if (pos < bcap) binned[b * bcap + pos] = s[k];
        }
    }
}

__global__ __launch_bounds__(256) void k_bin3(
        const int* __restrict__ rate_src, const int* __restrict__ rate_dst,
        const int* __restrict__ trust_src, const int* __restrict__ trust_dst,
        int* __restrict__ gcur_r, int2* __restrict__ binned_r,
        int* __restrict__ gcur_t, int2* __restrict__ binned_t,
        int* __restrict__ gcur_i, int* __restrict__ binned_i,
        int* __restrict__ gcur_u, int* __restrict__ binned_u) {
    int b = blockIdx.x;
    if (b < NB_SCATR) {
        scat_role(rate_src, rate_dst, ERATE, gcur_r, binned_r, BCAP_R, b);
    } else if (b < NB_SCATR + NB_SCATT) {
        scat_role(trust_dst, trust_src, ETRUST, gcur_t, binned_t, BCAP_T, b - NB_SCATR);
    } else if (b < NB_SCATR + NB_SCATT + NB_SCATI) {
        scat_key_role(rate_dst, ERATE, gcur_i, binned_i, BCAP_I, b - NB_SCATR - NB_SCATT);
    } else {
        scat_key_role(trust_src, ETRUST, gcur_u, binned_u, BCAP_U,
                      b - NB_SCATR - NB_SCATT - NB_SCATI);
    }
}

// rate CSR build: values are item ids < 65536 -> ushort
__device__ __forceinline__ void build_role_u16(const int2* __restrict__ binned, int bcap,
                                               const int* __restrict__ gcur,
                                               unsigned short* __restrict__ csr, int stride_c,
                                               int* __restrict__ cur_out, int b) {
    __shared__ int lcur[256];
    lcur[threadIdx.x] = 0;
    __syncthreads();
    int cnt = gcur[b]; if (cnt > bcap) cnt = bcap;
    for (int i = threadIdx.x; i < cnt; i += 256) {
        int2 e = binned[b * bcap + i];
        int u = e.x & 255;
        int p = atomicAdd(&lcur[u], 1);
        if (p < stride_c) csr[e.x * stride_c + p] = (unsigned short)e.y;
    }
    __syncthreads();
    int u = (b << 8) + threadIdx.x;
    if (u < UN) cur_out[u] = lcur[threadIdx.x];
}

__device__ __forceinline__ void build_role_i32(const int2* __restrict__ binned, int bcap,
                                               const int* __restrict__ gcur,
                                               int* __restrict__ csr, int stride_c,
                                               int* __restrict__ cur_out, int b) {
    __shared__ int lcur[256];
    lcur[threadIdx.x] = 0;
    __syncthreads();
    int cnt = gcur[b]; if (cnt > bcap) cnt = bcap;
    for (int i = threadIdx.x; i < cnt; i += 256) {
        int2 e = binned[b * bcap + i];
        int u = e.x & 255;
        int p = atomicAdd(&lcur[u], 1);
        if (p < stride_c) csr[e.x * stride_c + p] = e.y;
    }
    __syncthreads();
    int u = (b << 8) + threadIdx.x;
    if (u < UN) cur_out[u] = lcur[threadIdx.x];
}

__device__ __forceinline__ void count_role(const int* __restrict__ binned, int bcap,
                                           const int* __restrict__ gcur,
                                           int* __restrict__ deg_out, int limit, int b) {
    __shared__ int lcnt[256];
    lcnt[threadIdx.x] = 0;
    __syncthreads();
    int cnt = gcur[b]; if (cnt > bcap) cnt = bcap;
    for (int i = threadIdx.x; i < cnt; i += 256)
        atomicAdd(&lcnt[binned[b * bcap + i] & 255], 1);
    __syncthreads();
    int u = (b << 8) + threadIdx.x;
    if (u < limit) deg_out[u] = lcnt[threadIdx.x];
}

__global__ __launch_bounds__(256) void k_bin4(
        const int2* __restrict__ binned_r, const int* __restrict__ gcur_r,
        const int2* __restrict__ binned_t, const int* __restrict__ gcur_t,
        const int* __restrict__ binned_i, const int* __restrict__ gcur_i,
        const int* __restrict__ binned_u, const int* __restrict__ gcur_u,
        unsigned short* __restrict__ csr_r, int* __restrict__ cur_r,
        int* __restrict__ csr_t, int* __restrict__ cur_t,
        int* __restrict__ dri, int* __restrict__ dto) {
    int b = blockIdx.x;
    if (b < NB_BUILD) {
        build_role_u16(binned_r, BCAP_R, gcur_r, csr_r, STRIDE_R, cur_r, b);
    } else if (b < 2 * NB_BUILD) {
        build_role_i32(binned_t, BCAP_T, gcur_t, csr_t, STRIDE_T, cur_t, b - NB_BUILD);
    } else if (b < 2 * NB_BUILD + NB_CNTI) {
        count_role(binned_i, BCAP_I, gcur_i, dri, IN_, b - 2 * NB_BUILD);
    } else {
        count_role(binned_u, BCAP_U, gcur_u, dto, UN, b - 2 * NB_BUILD - NB_CNTI);
    }
}

// conv: yw_item -> yb_item, yw_user -> yb_user (f32 -> bf16)
__global__ __launch_bounds__(256) void k_conv(
        const float4* __restrict__ yw_item, const float4* __restrict__ yw_user,
        ushort4* __restrict__ yb_item, ushort4* __restrict__ yb_user) {
    int b = blockIdx.x;
    if (b < NB_CONVI) {
        int i = b * 256 + threadIdx.x;
        if (i < IN_ * DN / 4) {
            float4 v = yw_item[i];
            yb_item[i] = make_ushort4(f2bf(v.x), f2bf(v.y), f2bf(v.z), f2bf(v.w));
        }
    } else {
        int i = (b - NB_CONVI) * 256 + threadIdx.x;
        if (i < UN * DN / 4) {
            float4 v = yw_user[i];
            yb_user[i] = make_ushort4(f2bf(v.x), f2bf(v.y), f2bf(v.z), f2bf(v.w));
        }
    }
}

// B: link-loss (bf16 yw_user x f32 pq_user) | gather (all-bf16 rows, bf16 h out)
__global__ __launch_bounds__(256) void k_gathB(
        const float* __restrict__ pq_user, const unsigned short* __restrict__ yb_item,
        const unsigned short* __restrict__ yb_user,
        const int* __restrict__ cur_r, const unsigned short* __restrict__ csr_r,
        const int* __restrict__ cur_t, const int* __restrict__ csr_t,
        const int* __restrict__ trust_src, const int* __restrict__ trust_dst,
        double* __restrict__ acc,
        unsigned short* __restrict__ hb) {
    int b = blockIdx.x;
    if (b < NB_LINK) {
        int stride = NB_LINK * 256;
        float local = 0.0f;
        const int TOT = ETRUST * 16;
        for (int tid = b * 256 + threadIdx.x; tid < TOT; tid += stride) {
            int e = tid >> 4;
            int c = (tid & 15) << 2;
            int s = trust_src[e], d = trust_dst[e];
            ushort4 a = *reinterpret_cast<const ushort4*>(yb_user + ((long)s << 6) + c);
            float4 bb = *reinterpret_cast<const float4*>(pq_user + ((long)d << 6) + c);
            float dot = bf2f(a.x) * bb.x + bf2f(a.y) * bb.y
                      + bf2f(a.z) * bb.z + bf2f(a.w) * bb.w;
            #pragma unroll
            for (int off = 1; off < 16; off <<= 1) dot += __shfl_xor(dot, off);
            if ((tid & 15) == 0) { float dm = dot - 1.0f; local += dm * dm; }
        }
        #pragma unroll
        for (int off = 32; off > 0; off >>= 1) local += __shfl_xor(local, off);
        __shared__ float red[4];
        if ((threadIdx.x & 63) == 0) red[threadIdx.x >> 6] = local;
        __syncthreads();
        if (threadIdx.x == 0) unsafeAtomicAdd(acc, (double)(red[0] + red[1] + red[2] + red[3]));
        return;
    }
    int w = ((b - NB_LINK) << 2) + (threadIdx.x >> 6);
    if (w >= UN) return;
    int lane = threadIdx.x & 63;
    int grp = lane >> 4;
    int c4 = (lane & 15) << 2;

    float ax = 0.f, ay = 0.f, az = 0.f, aw = 0.f;
    float bx = 0.f, by = 0.f, bz = 0.f, bw = 0.f;
    float tx = 0.f, ty = 0.f, tz = 0.f, tw = 0.f;
    float ux = 0.f, uy = 0.f, uz = 0.f, uw = 0.f;
    int cr = cur_r[w]; if (cr > STRIDE_R) cr = STRIDE_R;
    int ct = cur_t[w]; if (ct > STRIDE_T) ct = STRIDE_T;

    {
        int my = (lane < cr) ? (int)csr_r[w * STRIDE_R + lane] : 0;
        for (int j = 0; j < cr; j += 8) {
            int e0 = j + grp;
            int e1 = j + 4 + grp;
            int r0 = __shfl(my, e0);       // full-wave shfl, sources defined
            int r1 = __shfl(my, e1);
            if (e0 < cr) {
                ushort4 v = *reinterpret_cast<const ushort4*>(yb_item + ((long)r0 << 6) + c4);
                ax += bf2f(v.x); ay += bf2f(v.y); az += bf2f(v.z); aw += bf2f(v.w);
            }
            if (e1 < cr) {
                ushort4 v = *reinterpret_cast<const ushort4*>(yb_item + ((long)r1 << 6) + c4);
                bx += bf2f(v.x); by += bf2f(v.y); bz += bf2f(v.z); bw += bf2f(v.w);
            }
        }
    }
    {
        int my = (lane < ct) ? csr_t[w * STRIDE_T + lane] : 0;
        for (int j = 0; j < ct; j += 8) {
            int e0 = j + grp;
            int e1 = j + 4 + grp;
            int r0 = __shfl(my, e0);
            int r1 = __shfl(my, e1);
            if (e0 < ct) {
                ushort4 v = *reinterpret_cast<const ushort4*>(yb_user + ((long)r0 << 6) + c4);
                tx += bf2f(v.x); ty += bf2f(v.y); tz += bf2f(v.z); tw += bf2f(v.w);
            }
            if (e1 < ct) {
                ushort4 v = *reinterpret_cast<const ushort4*>(yb_user + ((long)r1 << 6) + c4);
                ux += bf2f(v.x); uy += bf2f(v.y); uz += bf2f(v.z); uw += bf2f(v.w);
            }
        }
    }
    float fr = degfac_i(cr), ft = degfac_i(ct);
    float rx = fr * (ax + bx) + ft * (tx + ux);
    float ry = fr * (ay + by) + ft * (ty + uy);
    float rz = fr * (az + bz) + ft * (tz + uz);
    float rw = fr * (aw + bw) + ft * (tw + uw);
    rx += __shfl_xor(rx, 16); rx += __shfl_xor(rx, 32);
    ry += __shfl_xor(ry, 16); ry += __shfl_xor(ry, 32);
    rz += __shfl_xor(rz, 16); rz += __shfl_xor(rz, 32);
    rw += __shfl_xor(rw, 16); rw += __shfl_xor(rw, 32);
    if (grp == 0) {
        const float4 p = *reinterpret_cast<const float4*>(pq_user + ((long)w << 6) + c4);
        ushort4 o4 = make_ushort4(f2bf(p.x + rx), f2bf(p.y + ry),
                                  f2bf(p.z + rz), f2bf(p.w + rw));
        *reinterpret_cast<ushort4*>(hb + ((long)w << 6) + c4) = o4;
    }
}

// C: scores (bf16 h x f32 pq_item) | reg-loss (f32)
__global__ __launch_bounds__(256) void k_scorC(
        const unsigned short* __restrict__ hb,
        const float* __restrict__ pq_user, const float* __restrict__ yw_user,
        const float* __restrict__ pq_item, const float* __restrict__ yw_item,
        const float* __restrict__ b_user, const float* __restrict__ b_item,
        const float* __restrict__ gb,
        const int* __restrict__ ps, const int* __restrict__ pd,
        const int* __restrict__ ns, const int* __restrict__ nd,
        const int* __restrict__ cur_r, const int* __restrict__ cur_t,
        const int* __restrict__ dto, const int* __restrict__ dri,
        double* __restrict__ acc, float* __restrict__ out) {
    int b = blockIdx.x;
    if (b < NB_SCOR) {
        int g = (b * 256 + threadIdx.x) >> 4;
        int c = (threadIdx.x & 15) << 2;
        int e0 = g * 2, e1 = g * 2 + 1;
        bool p0 = e0 < EPRED, p1 = e1 < EPRED;
        int i0 = p0 ? e0 : e0 - EPRED;
        int i1 = p1 ? e1 : e1 - EPRED;
        int s0 = (p0 ? ps : ns)[i0];
        int d0 = (p0 ? pd : nd)[i0];
        int s1 = (p1 ? ps : ns)[i1];
        int d1 = (p1 ? pd : nd)[i1];
        ushort4 ha = *reinterpret_cast<const ushort4*>(hb + ((long)s0 << 6) + c);
        float4  ia = *reinterpret_cast<const float4*>(pq_item + ((long)d0 << 6) + c);
        ushort4 hc = *reinterpret_cast<const ushort4*>(hb + ((long)s1 << 6) + c);
        float4  ib = *reinterpret_cast<const float4*>(pq_item + ((long)d1 << 6) + c);
        float dot0 = bf2f(ha.x) * ia.x + bf2f(ha.y) * ia.y
                   + bf2f(ha.z) * ia.z + bf2f(ha.w) * ia.w;
        float dot1 = bf2f(hc.x) * ib.x + bf2f(hc.y) * ib.y
                   + bf2f(hc.z) * ib.z + bf2f(hc.w) * ib.w;
        #pragma unroll
        for (int off = 1; off < 16; off <<= 1) {
            dot0 += __shfl_xor(dot0, off);
            dot1 += __shfl_xor(dot1, off);
        }
        if ((threadIdx.x & 15) == 0) {
            float g0 = gb[0];
            float2 o2 = make_float2(dot0 + b_user[s0] + b_item[d0] + g0,
                                    dot1 + b_user[s1] + b_item[d1] + g0);
            *reinterpret_cast<float2*>(out + e0) = o2;
        }
    } else {
        int rb = b - NB_SCOR;
        int stride = NB_REG * 256;
        float local = 0.0f;
        const int TOT = (UN + IN_) * 16;
        for (int tid = rb * 256 + threadIdx.x; tid < TOT; tid += stride) {
            int r = tid >> 4;
            int c = (tid & 15) << 2;
            if (r < UN) {
                float4 p = *reinterpret_cast<const float4*>(pq_user + ((long)r << 6) + c);
                float4 y = *reinterpret_cast<const float4*>(yw_user + ((long)r << 6) + c);
                float sp = p.x * p.x + p.y * p.y + p.z * p.z + p.w * p.w;
                float sy = y.x * y.x + y.y * y.y + y.z * y.z + y.w * y.w;
                #pragma unroll
                for (int off = 1; off < 16; off <<= 1) {
                    sp += __shfl_xor(sp, off);
                    sy += __shfl_xor(sy, off);
                }
                if ((tid & 15) == 0) {
                    float Iu  = degfac_i(cur_r[r]);
                    float Tu  = degfac_i(cur_t[r]);
                    float Tvp = degfac_i(dto[r]);
                    float bb  = b_user[r];
                    local += ((LAMDA * Iu) * (bb * bb)
                            + (LAMDA * Iu + LAMDA_T * Tu) * sp
                            + (LAMDA_T * Tvp) * sy) * (1.0f / UN);
                }
            } else {
                int it = r - UN;
                float4 p = *reinterpret_cast<const float4*>(pq_item + ((long)it << 6) + c);
                float4 y = *reinterpret_cast<const float4*>(yw_item + ((long)it << 6) + c);
                float sp = p.x * p.x + p.y * p.y + p.z * p.z + p.w * p.w;
                float sy = y.x * y.x + y.y * y.y + y.z * y.z + y.w * y.w;
                #pragma unroll
                for (int off = 1; off < 16; off <<= 1) {
                    sp += __shfl_xor(sp, off);
                    sy += __shfl_xor(sy, off);
                }
                if ((tid & 15) == 0) {
                    float Uj = degfac_i(dri[it]);
                    float bb = b_item[it];
                    local += (LAMDA * Uj) * (bb * bb + sp + sy) * (1.0f / IN_);
                }
            }
        }
        #pragma unroll
        for (int off = 32; off > 0; off >>= 1) local += __shfl_xor(local, off);
        __shared__ float red[4];
        if ((threadIdx.x & 63) == 0) red[threadIdx.x >> 6] = local;
        __syncthreads();
        if (threadIdx.x == 0) unsafeAtomicAdd(acc + 1, (double)(red[0] + red[1] + red[2] + red[3]));
    }
}

__global__ void k_final(const double* __restrict__ acc, float* __restrict__ out) {
    if (threadIdx.x == 0 && blockIdx.x == 0) {
        out[2 * EPRED]     = (float)acc[1];
        out[2 * EPRED + 1] = (float)(LAMDA_T * acc[0] / (double)ETRUST);
    }
}

extern "C" void kernel_launch(void* const* d_in, const int* in_sizes, int n_in,
                              void* d_out, int out_size, void* d_ws, size_t ws_size,
                              hipStream_t stream) {
    const float* pq_user = (const float*)d_in[0];
    const float* pq_item = (const float*)d_in[1];
    const float* yw_user = (const float*)d_in[2];
    const float* yw_item = (const float*)d_in[3];
    const float* b_user  = (const float*)d_in[4];
    const float* b_item  = (const float*)d_in[5];
    const float* gb      = (const float*)d_in[6];
    const int* rate_src  = (const int*)d_in[7];
    const int* rate_dst  = (const int*)d_in[8];
    const int* trust_src = (const int*)d_in[9];
    const int* trust_dst = (const int*)d_in[10];
    const int* pos_src   = (const int*)d_in[11];
    const int* pos_dst   = (const int*)d_in[12];
    const int* neg_src   = (const int*)d_in[13];
    const int* neg_dst   = (const int*)d_in[14];

    int*   wsi   = (int*)d_ws;
    unsigned short* yb_item = (unsigned short*)d_ws;
    unsigned short* yb_user = (unsigned short*)((char*)d_ws + OFF_YBU_B);
    unsigned short* hb      = (unsigned short*)((char*)d_ws + OFF_HB_B);
    int2*  binned_r = (int2*)wsi;
    int2*  binned_t = (int2*)(wsi + OFF_BIN_T_W);
    int*   binned_i = wsi + OFF_BIN_I_W;
    int*   binned_u = wsi + OFF_BIN_U_W;
    int*   gcur_r = wsi + OFF_GCURR_W;
    int*   gcur_t = wsi + OFF_GCURT_W;
    int*   gcur_i = wsi + OFF_GCURI_W;
    int*   gcur_u = wsi + OFF_GCURU_W;
    unsigned short* csr_r = (unsigned short*)((char*)d_ws + OFF_CSR_R_B);
    int*   csr_t  = wsi + OFF_CSR_T;
    int*   dri    = wsi + OFF_DRI;
    int*   dto    = wsi + OFF_DTO;
    int*   cur_r  = wsi + OFF_CURR;
    int*   cur_t  = wsi + OFF_CURT;
    double* acc   = (double*)((char*)d_ws + OFF_ACC_B);
    float* out    = (float*)d_out;

    // 1. zero gcur block + acc
    k_zero<<<6, 256, 0, stream>>>(gcur_r, 1400);
    k_zero<<<1, 64, 0, stream>>>((int*)acc, 4);
    // 2. bin3: LDS-ranked scatters
    k_bin3<<<NB_SCATR + NB_SCATT + NB_SCATI + NB_SCATU, 256, 0, stream>>>(
        rate_src, rate_dst, trust_src, trust_dst,
        gcur_r, binned_r, gcur_t, binned_t,
        gcur_i, binned_i, gcur_u, binned_u);
    // 3. bin4: CSR builds (u16 rate / i32 trust) + degree counts
    k_bin4<<<2 * NB_BUILD + NB_CNTI + NB_CNTU, 256, 0, stream>>>(
        binned_r, gcur_r, binned_t, gcur_t, binned_i, gcur_i, binned_u, gcur_u,
        csr_r, cur_r, csr_t, cur_t, dri, dto);
    // 4. conv: yw_item + yw_user -> bf16 (into dead binned region)
    k_conv<<<NB_CONVI + NB_CONVU, 256, 0, stream>>>(
        (const float4*)yw_item, (const float4*)yw_user,
        (ushort4*)yb_item, (ushort4*)yb_user);
    // 5. B: link (bf16 x f32) + gather (bf16 rows both sides, bf16 h out)
    k_gathB<<<NB_LINK + NB_GATH, 256, 0, stream>>>(
        pq_user, yb_item, yb_user, cur_r, csr_r, cur_t, csr_t,
        trust_src, trust_dst, acc, hb);
    // 6. C: scores (bf16 h) + reg loss (f32)
    k_scorC<<<NB_SCOR + NB_REG, 256, 0, stream>>>(
        hb, pq_user, yw_user, pq_item, yw_item, b_user, b_item, gb,
        pos_src, pos_dst, neg_src, neg_dst,
        cur_r, cur_t, dto, dri, acc, out);
    // 7. finalize
    k_final<<<1, 64, 0, stream>>>(acc, out);
}